// Round 6
// baseline (36.964 us; speedup 1.0000x reference)
//
#include <hip/hip_runtime.h>

// compile-time DPP move: dest lane gets src lane per CTRL pattern
template<int CTRL>
__device__ __forceinline__ float dppmov(float x) {
    return __builtin_bit_cast(float,
        __builtin_amdgcn_update_dpp(0, __builtin_bit_cast(int, x),
                                    CTRL, 0xf, 0xf, true));
}
#define DPP_XOR1  0xB1   // quad_perm [1,0,3,2]
#define DPP_XOR2  0x4E   // quad_perm [2,3,0,1]
#define DPP_XOR8  0x128  // row_ror:8 == lane^8 within 16-lane rows
#define DPP_SHR(d) (0x110 | (d))

__device__ __forceinline__ void pen1(const float4& r, const float4& c,
                                     float& mi, float& mj)
{
    float dx = r.x - c.x, dy = r.y - c.y, dz = r.z - c.z;
    float d2 = fmaf(dx, dx, fmaf(dy, dy, dz * dz));
    float p  = r.w + c.w - __builtin_amdgcn_sqrtf(d2);
    mi = fmaxf(mi, p);
    mj = fmaxf(mj, p);
}

// ---------------------------------------------------------------------------
// Fully fused, ONE batch per wave (4 waves / block, 2048 blocks = 8 blocks/CU).
// Register budget engineered for <=64 VGPR -> 8 waves/SIMD (the 64-reg
// occupancy cliff is the whole point of this version):
//   pair phase: m[16] + cs[7] float4 (28) + rs (4) + addr/temps ~10  = ~58
//   FK phase:   F(9)+R(9)+t(3)+trig/axes(6)+temps(8)                 = ~35
//  - FK prefix product via DPP row_shr on the VALU pipe (4x lane-redundant,
//    accepted: scan is ~15% of issue; concurrency is worth more).
//  - Spheres in padded LDS (stride 9 float4), wave-private slice, no barrier.
//  - Pair loop: two 7-column register-tiled passes, unpacked pen1,
//    lane owns (row sr = L>>3, col sc = L&7); 105 compile-time (i,j) pairs.
//  - Per-link wave max: log-fold, 13 DPP + 2 DS + xor16/xor32 merges.
// ---------------------------------------------------------------------------
__global__ __launch_bounds__(256, 8) void fused_kernel(
    const float* __restrict__ q,        // [B,16]
    const float* __restrict__ frot,     // [16,3,3]
    const float* __restrict__ ftrans,   // [16,3]
    const float* __restrict__ axes,     // [16,3]
    const float* __restrict__ spheres,  // [16,8,4]
    float* __restrict__ out,            // [B,16]
    int B)
{
    __shared__ float4 sph[4][16 * 9];   // per-wave slice, 9 float4/link pad
    const int t    = threadIdx.x;
    const int w    = t >> 6;
    const int lane = t & 63;
    int b = blockIdx.x * 4 + w;
    const bool alive = (b < B);
    if (!alive) b = B - 1;

    const int l = lane & 15;            // link this lane owns in FK phase
    const int g = lane >> 4;            // sphere-group (2 spheres each)

    // ---- local joint transform: R = F * J(axis,q)
    const float qv = q[(size_t)b * 16 + l];
    const float s = __sinf(qv), c = __cosf(qv), oc = 1.0f - c;
    const float ax = axes[3*l+0], ay = axes[3*l+1], az = axes[3*l+2];

    const float F00=frot[9*l+0], F01=frot[9*l+1], F02=frot[9*l+2];
    const float F10=frot[9*l+3], F11=frot[9*l+4], F12=frot[9*l+5];
    const float F20=frot[9*l+6], F21=frot[9*l+7], F22=frot[9*l+8];

    float R00,R01,R02,R10,R11,R12,R20,R21,R22;
    {
        float u0 = fmaf(F01,az, -F02*ay);
        float u1 = fmaf(F02,ax, -F00*az);
        float u2 = fmaf(F00,ay, -F01*ax);
        float v0 = fmaf(u1,az, -u2*ay);
        float v1 = fmaf(u2,ax, -u0*az);
        float v2 = fmaf(u0,ay, -u1*ax);
        R00 = fmaf(oc,v0, fmaf(s,u0, F00));
        R01 = fmaf(oc,v1, fmaf(s,u1, F01));
        R02 = fmaf(oc,v2, fmaf(s,u2, F02));

        u0 = fmaf(F11,az, -F12*ay);
        u1 = fmaf(F12,ax, -F10*az);
        u2 = fmaf(F10,ay, -F11*ax);
        v0 = fmaf(u1,az, -u2*ay);
        v1 = fmaf(u2,ax, -u0*az);
        v2 = fmaf(u0,ay, -u1*ax);
        R10 = fmaf(oc,v0, fmaf(s,u0, F10));
        R11 = fmaf(oc,v1, fmaf(s,u1, F11));
        R12 = fmaf(oc,v2, fmaf(s,u2, F12));

        u0 = fmaf(F21,az, -F22*ay);
        u1 = fmaf(F22,ax, -F20*az);
        u2 = fmaf(F20,ay, -F21*ax);
        v0 = fmaf(u1,az, -u2*ay);
        v1 = fmaf(u2,ax, -u0*az);
        v2 = fmaf(u0,ay, -u1*ax);
        R20 = fmaf(oc,v0, fmaf(s,u0, F20));
        R21 = fmaf(oc,v1, fmaf(s,u1, F21));
        R22 = fmaf(oc,v2, fmaf(s,u2, F22));
    }
    float t0 = ftrans[3*l+0], t1 = ftrans[3*l+1], t2 = ftrans[3*l+2];

    // ---- Kogge-Stone prefix product over width-16 segments (DPP row_shr)
    #define SCAN_STEP(D, CTRL)                                                  \
    {                                                                           \
        float P00 = dppmov<CTRL>(R00), P01 = dppmov<CTRL>(R01), P02 = dppmov<CTRL>(R02); \
        float P10 = dppmov<CTRL>(R10), P11 = dppmov<CTRL>(R11), P12 = dppmov<CTRL>(R12); \
        float P20 = dppmov<CTRL>(R20), P21 = dppmov<CTRL>(R21), P22 = dppmov<CTRL>(R22); \
        float pt0 = dppmov<CTRL>(t0),  pt1 = dppmov<CTRL>(t1),  pt2 = dppmov<CTRL>(t2);  \
        if (l >= (D)) {                                                         \
            float n00 = fmaf(P00,R00, fmaf(P01,R10, P02*R20));                  \
            float n01 = fmaf(P00,R01, fmaf(P01,R11, P02*R21));                  \
            float n02 = fmaf(P00,R02, fmaf(P01,R12, P02*R22));                  \
            float n10 = fmaf(P10,R00, fmaf(P11,R10, P12*R20));                  \
            float n11 = fmaf(P10,R01, fmaf(P11,R11, P12*R21));                  \
            float n12 = fmaf(P10,R02, fmaf(P11,R12, P12*R22));                  \
            float n20 = fmaf(P20,R00, fmaf(P21,R10, P22*R20));                  \
            float n21 = fmaf(P20,R01, fmaf(P21,R11, P22*R21));                  \
            float n22 = fmaf(P20,R02, fmaf(P21,R12, P22*R22));                  \
            float nt0 = fmaf(P00,t0, fmaf(P01,t1, fmaf(P02,t2, pt0)));          \
            float nt1 = fmaf(P10,t0, fmaf(P11,t1, fmaf(P12,t2, pt1)));          \
            float nt2 = fmaf(P20,t0, fmaf(P21,t1, fmaf(P22,t2, pt2)));          \
            R00=n00; R01=n01; R02=n02;                                          \
            R10=n10; R11=n11; R12=n12;                                          \
            R20=n20; R21=n21; R22=n22;                                          \
            t0=nt0; t1=nt1; t2=nt2;                                             \
        }                                                                       \
    }
    SCAN_STEP(1, DPP_SHR(1))
    SCAN_STEP(2, DPP_SHR(2))
    SCAN_STEP(4, DPP_SHR(4))
    SCAN_STEP(8, DPP_SHR(8))
    #undef SCAN_STEP

    // ---- transform this lane's 2 spheres of link l into padded LDS
    #pragma unroll
    for (int k = 0; k < 2; ++k) {
        const int sp = g * 2 + k;
        float4 cs = reinterpret_cast<const float4*>(spheres)[l*8 + sp];
        float wx = fmaf(R00,cs.x, fmaf(R01,cs.y, fmaf(R02,cs.z, t0)));
        float wy = fmaf(R10,cs.x, fmaf(R11,cs.y, fmaf(R12,cs.z, t1)));
        float wz = fmaf(R20,cs.x, fmaf(R21,cs.y, fmaf(R22,cs.z, t2)));
        sph[w][l*9 + sp] = make_float4(wx, wy, wz, cs.w);
    }
    // wave-private LDS slice: drain this wave's writes, no block barrier
    asm volatile("s_waitcnt lgkmcnt(0)" ::: "memory");

    // ---- pairwise penetration, per-link max (64 lanes on one batch)
    const float4* S = sph[w];
    const int sr = lane >> 3;      // row sphere 0..7
    const int sc = lane & 7;       // col sphere 0..7

    float m[16];
    #pragma unroll
    for (int k = 0; k < 16; ++k) m[k] = -100.0f;

    // Pass A: columns j in [2,8], rows i in [0,6]
    {
        float4 cs[7];
        #pragma unroll
        for (int j = 2; j <= 8; ++j) cs[j-2] = S[j*9 + sc];
        #pragma unroll
        for (int i = 0; i <= 6; ++i) {
            float4 rs = S[i*9 + sr];
            #pragma unroll
            for (int j = i + 2; j <= 8; ++j)
                pen1(rs, cs[j-2], m[i], m[j]);
        }
    }
    // Pass B: columns j in [9,15], rows i in [0,13]
    {
        float4 cs[7];
        #pragma unroll
        for (int j = 9; j <= 15; ++j) cs[j-9] = S[j*9 + sc];
        #pragma unroll
        for (int i = 0; i <= 13; ++i) {
            float4 rs = S[i*9 + sr];
            const int j0 = (i + 2 > 9) ? (i + 2) : 9;
            #pragma unroll
            for (int j = 9; j <= 15; ++j) {
                if (j < j0) continue;
                pen1(rs, cs[j-9], m[i], m[j]);
            }
        }
    }

    // ---- log-fold wave reduction (13 DPP + 2 DS + final merges)
    {
        int bit0 = lane & 1;
        #pragma unroll
        for (int k = 0; k < 8; ++k) {
            float send = bit0 ? m[k] : m[k+8];
            float recv = dppmov<DPP_XOR1>(send);
            m[k] = fmaxf(bit0 ? m[k+8] : m[k], recv);
        }
        int bit1 = (lane >> 1) & 1;
        #pragma unroll
        for (int k = 0; k < 4; ++k) {
            float send = bit1 ? m[k] : m[k+4];
            float recv = dppmov<DPP_XOR2>(send);
            m[k] = fmaxf(bit1 ? m[k+4] : m[k], recv);
        }
        int bit2 = (lane >> 2) & 1;
        #pragma unroll
        for (int k = 0; k < 2; ++k) {
            float send = bit2 ? m[k] : m[k+2];
            float recv = __shfl_xor(send, 4, 64);
            m[k] = fmaxf(bit2 ? m[k+2] : m[k], recv);
        }
        int bit3 = (lane >> 3) & 1;
        {
            float send = bit3 ? m[0] : m[1];
            float recv = dppmov<DPP_XOR8>(send);
            m[0] = fmaxf(bit3 ? m[1] : m[0], recv);
        }
        float v = m[0];
        v = fmaxf(v, __shfl_xor(v, 16, 64));
        v = fmaxf(v, __shfl_xor(v, 32, 64));
        m[0] = v;
    }

    if (alive && lane < 16) {
        // link index = bit-reversal of lane's low 4 bits
        int k = ((lane & 1) << 3) | ((lane & 2) << 1) | ((lane & 4) >> 1) | ((lane & 8) >> 3);
        out[(size_t)b * 16 + k] = m[0];
    }
}

// ---------------------------------------------------------------------------
extern "C" void kernel_launch(void* const* d_in, const int* in_sizes, int n_in,
                              void* d_out, int out_size, void* d_ws, size_t ws_size,
                              hipStream_t stream) {
    const float* q      = (const float*)d_in[0];
    const float* frot   = (const float*)d_in[1];
    const float* ftrans = (const float*)d_in[2];
    const float* axes   = (const float*)d_in[3];
    const float* sphere = (const float*)d_in[4];
    float* out = (float*)d_out;

    const int B = in_sizes[0] / 16;
    const int blocks = (B + 3) / 4;     // 1 batch per wave, 4 per block
    fused_kernel<<<dim3(blocks), dim3(256), 0, stream>>>(
        q, frot, ftrans, axes, sphere, out, B);
}

// Round 7
// 28.526 us; speedup vs baseline: 1.2958x; 1.2958x over previous
//
#include <hip/hip_runtime.h>

// compile-time DPP move: dest lane gets src lane per CTRL pattern
template<int CTRL>
__device__ __forceinline__ float dppmov(float x) {
    return __builtin_bit_cast(float,
        __builtin_amdgcn_update_dpp(0, __builtin_bit_cast(int, x),
                                    CTRL, 0xf, 0xf, true));
}
#define DPP_XOR1  0xB1   // quad_perm [1,0,3,2]
#define DPP_XOR2  0x4E   // quad_perm [2,3,0,1]
#define DPP_XOR8  0x128  // row_ror:8 == lane^8 within 16-lane rows
#define DPP_SHR(d) (0x110 | (d))

__device__ __forceinline__ void pen1(const float4& r, const float4& c,
                                     float& mi, float& mj)
{
    float dx = r.x - c.x, dy = r.y - c.y, dz = r.z - c.z;
    float d2 = fmaf(dx, dx, fmaf(dy, dy, dz * dz));
    float p  = r.w + c.w - __builtin_amdgcn_sqrtf(d2);
    mi = fmaxf(mi, p);
    mj = fmaxf(mj, p);
}

// ---------------------------------------------------------------------------
// Fully fused, ONE batch per wave (4 waves / block).
// __launch_bounds__(256, 6): VGPR cap = floor(512/6) = 85 -> 6 waves/SIMD.
// (R6's cap of 64 regs caused catastrophic scratch spills: 150 MB of
// FETCH+WRITE. This body needs ~80 regs; 85 is the feasible occupancy step.)
//  - FK prefix product via DPP row_shr on the VALU pipe.
//  - Spheres in padded LDS (stride 9 float4), wave-private slice, no barrier.
//  - Pair loop: two 7-column register-tiled passes, unpacked pen1,
//    lane owns (row sr = L>>3, col sc = L&7); 105 compile-time (i,j) pairs.
//  - Per-link wave max: log-fold, 13 DPP + 2 DS + xor16/xor32 merges.
// ---------------------------------------------------------------------------
__global__ __launch_bounds__(256, 6) void fused_kernel(
    const float* __restrict__ q,        // [B,16]
    const float* __restrict__ frot,     // [16,3,3]
    const float* __restrict__ ftrans,   // [16,3]
    const float* __restrict__ axes,     // [16,3]
    const float* __restrict__ spheres,  // [16,8,4]
    float* __restrict__ out,            // [B,16]
    int B)
{
    __shared__ float4 sph[4][16 * 9];   // per-wave slice, 9 float4/link pad
    const int t    = threadIdx.x;
    const int w    = t >> 6;
    const int lane = t & 63;
    int b = blockIdx.x * 4 + w;
    const bool alive = (b < B);
    if (!alive) b = B - 1;

    const int l = lane & 15;            // link this lane owns in FK phase
    const int g = lane >> 4;            // sphere-group (2 spheres each)

    // ---- local joint transform: R = F * J(axis,q)
    const float qv = q[(size_t)b * 16 + l];
    const float s = __sinf(qv), c = __cosf(qv), oc = 1.0f - c;
    const float ax = axes[3*l+0], ay = axes[3*l+1], az = axes[3*l+2];

    const float F00=frot[9*l+0], F01=frot[9*l+1], F02=frot[9*l+2];
    const float F10=frot[9*l+3], F11=frot[9*l+4], F12=frot[9*l+5];
    const float F20=frot[9*l+6], F21=frot[9*l+7], F22=frot[9*l+8];

    float R00,R01,R02,R10,R11,R12,R20,R21,R22;
    {
        float u0 = fmaf(F01,az, -F02*ay);
        float u1 = fmaf(F02,ax, -F00*az);
        float u2 = fmaf(F00,ay, -F01*ax);
        float v0 = fmaf(u1,az, -u2*ay);
        float v1 = fmaf(u2,ax, -u0*az);
        float v2 = fmaf(u0,ay, -u1*ax);
        R00 = fmaf(oc,v0, fmaf(s,u0, F00));
        R01 = fmaf(oc,v1, fmaf(s,u1, F01));
        R02 = fmaf(oc,v2, fmaf(s,u2, F02));

        u0 = fmaf(F11,az, -F12*ay);
        u1 = fmaf(F12,ax, -F10*az);
        u2 = fmaf(F10,ay, -F11*ax);
        v0 = fmaf(u1,az, -u2*ay);
        v1 = fmaf(u2,ax, -u0*az);
        v2 = fmaf(u0,ay, -u1*ax);
        R10 = fmaf(oc,v0, fmaf(s,u0, F10));
        R11 = fmaf(oc,v1, fmaf(s,u1, F11));
        R12 = fmaf(oc,v2, fmaf(s,u2, F12));

        u0 = fmaf(F21,az, -F22*ay);
        u1 = fmaf(F22,ax, -F20*az);
        u2 = fmaf(F20,ay, -F21*ax);
        v0 = fmaf(u1,az, -u2*ay);
        v1 = fmaf(u2,ax, -u0*az);
        v2 = fmaf(u0,ay, -u1*ax);
        R20 = fmaf(oc,v0, fmaf(s,u0, F20));
        R21 = fmaf(oc,v1, fmaf(s,u1, F21));
        R22 = fmaf(oc,v2, fmaf(s,u2, F22));
    }
    float t0 = ftrans[3*l+0], t1 = ftrans[3*l+1], t2 = ftrans[3*l+2];

    // ---- Kogge-Stone prefix product over width-16 segments (DPP row_shr)
    #define SCAN_STEP(D, CTRL)                                                  \
    {                                                                           \
        float P00 = dppmov<CTRL>(R00), P01 = dppmov<CTRL>(R01), P02 = dppmov<CTRL>(R02); \
        float P10 = dppmov<CTRL>(R10), P11 = dppmov<CTRL>(R11), P12 = dppmov<CTRL>(R12); \
        float P20 = dppmov<CTRL>(R20), P21 = dppmov<CTRL>(R21), P22 = dppmov<CTRL>(R22); \
        float pt0 = dppmov<CTRL>(t0),  pt1 = dppmov<CTRL>(t1),  pt2 = dppmov<CTRL>(t2);  \
        if (l >= (D)) {                                                         \
            float n00 = fmaf(P00,R00, fmaf(P01,R10, P02*R20));                  \
            float n01 = fmaf(P00,R01, fmaf(P01,R11, P02*R21));                  \
            float n02 = fmaf(P00,R02, fmaf(P01,R12, P02*R22));                  \
            float n10 = fmaf(P10,R00, fmaf(P11,R10, P12*R20));                  \
            float n11 = fmaf(P10,R01, fmaf(P11,R11, P12*R21));                  \
            float n12 = fmaf(P10,R02, fmaf(P11,R12, P12*R22));                  \
            float n20 = fmaf(P20,R00, fmaf(P21,R10, P22*R20));                  \
            float n21 = fmaf(P20,R01, fmaf(P21,R11, P22*R21));                  \
            float n22 = fmaf(P20,R02, fmaf(P21,R12, P22*R22));                  \
            float nt0 = fmaf(P00,t0, fmaf(P01,t1, fmaf(P02,t2, pt0)));          \
            float nt1 = fmaf(P10,t0, fmaf(P11,t1, fmaf(P12,t2, pt1)));          \
            float nt2 = fmaf(P20,t0, fmaf(P21,t1, fmaf(P22,t2, pt2)));          \
            R00=n00; R01=n01; R02=n02;                                          \
            R10=n10; R11=n11; R12=n12;                                          \
            R20=n20; R21=n21; R22=n22;                                          \
            t0=nt0; t1=nt1; t2=nt2;                                             \
        }                                                                       \
    }
    SCAN_STEP(1, DPP_SHR(1))
    SCAN_STEP(2, DPP_SHR(2))
    SCAN_STEP(4, DPP_SHR(4))
    SCAN_STEP(8, DPP_SHR(8))
    #undef SCAN_STEP

    // ---- transform this lane's 2 spheres of link l into padded LDS
    #pragma unroll
    for (int k = 0; k < 2; ++k) {
        const int sp = g * 2 + k;
        float4 cs = reinterpret_cast<const float4*>(spheres)[l*8 + sp];
        float wx = fmaf(R00,cs.x, fmaf(R01,cs.y, fmaf(R02,cs.z, t0)));
        float wy = fmaf(R10,cs.x, fmaf(R11,cs.y, fmaf(R12,cs.z, t1)));
        float wz = fmaf(R20,cs.x, fmaf(R21,cs.y, fmaf(R22,cs.z, t2)));
        sph[w][l*9 + sp] = make_float4(wx, wy, wz, cs.w);
    }
    // wave-private LDS slice: drain this wave's writes, no block barrier
    asm volatile("s_waitcnt lgkmcnt(0)" ::: "memory");

    // ---- pairwise penetration, per-link max (64 lanes on one batch)
    const float4* S = sph[w];
    const int sr = lane >> 3;      // row sphere 0..7
    const int sc = lane & 7;       // col sphere 0..7

    float m[16];
    #pragma unroll
    for (int k = 0; k < 16; ++k) m[k] = -100.0f;

    // Pass A: columns j in [2,8], rows i in [0,6]
    {
        float4 cs[7];
        #pragma unroll
        for (int j = 2; j <= 8; ++j) cs[j-2] = S[j*9 + sc];
        #pragma unroll
        for (int i = 0; i <= 6; ++i) {
            float4 rs = S[i*9 + sr];
            #pragma unroll
            for (int j = i + 2; j <= 8; ++j)
                pen1(rs, cs[j-2], m[i], m[j]);
        }
    }
    // Pass B: columns j in [9,15], rows i in [0,13]
    {
        float4 cs[7];
        #pragma unroll
        for (int j = 9; j <= 15; ++j) cs[j-9] = S[j*9 + sc];
        #pragma unroll
        for (int i = 0; i <= 13; ++i) {
            float4 rs = S[i*9 + sr];
            const int j0 = (i + 2 > 9) ? (i + 2) : 9;
            #pragma unroll
            for (int j = 9; j <= 15; ++j) {
                if (j < j0) continue;
                pen1(rs, cs[j-9], m[i], m[j]);
            }
        }
    }

    // ---- log-fold wave reduction (13 DPP + 2 DS + final merges)
    {
        int bit0 = lane & 1;
        #pragma unroll
        for (int k = 0; k < 8; ++k) {
            float send = bit0 ? m[k] : m[k+8];
            float recv = dppmov<DPP_XOR1>(send);
            m[k] = fmaxf(bit0 ? m[k+8] : m[k], recv);
        }
        int bit1 = (lane >> 1) & 1;
        #pragma unroll
        for (int k = 0; k < 4; ++k) {
            float send = bit1 ? m[k] : m[k+4];
            float recv = dppmov<DPP_XOR2>(send);
            m[k] = fmaxf(bit1 ? m[k+4] : m[k], recv);
        }
        int bit2 = (lane >> 2) & 1;
        #pragma unroll
        for (int k = 0; k < 2; ++k) {
            float send = bit2 ? m[k] : m[k+2];
            float recv = __shfl_xor(send, 4, 64);
            m[k] = fmaxf(bit2 ? m[k+2] : m[k], recv);
        }
        int bit3 = (lane >> 3) & 1;
        {
            float send = bit3 ? m[0] : m[1];
            float recv = dppmov<DPP_XOR8>(send);
            m[0] = fmaxf(bit3 ? m[1] : m[0], recv);
        }
        float v = m[0];
        v = fmaxf(v, __shfl_xor(v, 16, 64));
        v = fmaxf(v, __shfl_xor(v, 32, 64));
        m[0] = v;
    }

    if (alive && lane < 16) {
        // link index = bit-reversal of lane's low 4 bits
        int k = ((lane & 1) << 3) | ((lane & 2) << 1) | ((lane & 4) >> 1) | ((lane & 8) >> 3);
        out[(size_t)b * 16 + k] = m[0];
    }
}

// ---------------------------------------------------------------------------
extern "C" void kernel_launch(void* const* d_in, const int* in_sizes, int n_in,
                              void* d_out, int out_size, void* d_ws, size_t ws_size,
                              hipStream_t stream) {
    const float* q      = (const float*)d_in[0];
    const float* frot   = (const float*)d_in[1];
    const float* ftrans = (const float*)d_in[2];
    const float* axes   = (const float*)d_in[3];
    const float* sphere = (const float*)d_in[4];
    float* out = (float*)d_out;

    const int B = in_sizes[0] / 16;
    const int blocks = (B + 3) / 4;     // 1 batch per wave, 4 per block
    fused_kernel<<<dim3(blocks), dim3(256), 0, stream>>>(
        q, frot, ftrans, axes, sphere, out, B);
}